// Round 7
// baseline (853.482 us; speedup 1.0000x reference)
//
#include <hip/hip_runtime.h>
#include <cfloat>
#include <cmath>

#define F_IN 128
#define HID 512

typedef short bf16x8 __attribute__((ext_vector_type(8)));
typedef float f32x4 __attribute__((ext_vector_type(4)));

// ---- bf16 split helpers (RNE) ----
__device__ static inline void split_bf16(float v, short& hi, short& lo) {
    unsigned u = __float_as_uint(v);
    unsigned r = u + 0x7FFF + ((u >> 16) & 1);
    hi = (short)(r >> 16);
    float hf = __uint_as_float(((unsigned)(unsigned short)hi) << 16);
    float res = v - hf;
    unsigned u2 = __float_as_uint(res);
    unsigned r2 = u2 + 0x7FFF + ((u2 >> 16) & 1);
    lo = (short)(r2 >> 16);
}

__device__ static inline void gload_lds16(const void* g, void* l) {
    __builtin_amdgcn_global_load_lds(
        (const __attribute__((address_space(1))) unsigned int*)g,
        (__attribute__((address_space(3))) unsigned int*)l,
        16, 0, 0);
}

// ---------------- small utility kernels ----------------

__global__ void zero_kernel(int* __restrict__ a, int n) {
    int i = blockIdx.x * blockDim.x + threadIdx.x;
    if (i < n) a[i] = 0;
}

__global__ void count_in_kernel(const int* __restrict__ dst, int* __restrict__ cnt, int E) {
    int e = blockIdx.x * blockDim.x + threadIdx.x;
    if (e < E) atomicAdd(&cnt[dst[e]], 1);
}

// single-block scan (exclusive prefix sum); also writes offs[n] = total
__global__ void scan_kernel(const int* __restrict__ cnt, int* __restrict__ offs, int n) {
    __shared__ int buf[1024];
    __shared__ int carry_s;
    if (threadIdx.x == 0) carry_s = 0;
    __syncthreads();
    for (int base = 0; base < n; base += 1024) {
        int i = base + threadIdx.x;
        int v = (i < n) ? cnt[i] : 0;
        buf[threadIdx.x] = v;
        __syncthreads();
        for (int s = 1; s < 1024; s <<= 1) {
            int t = (threadIdx.x >= s) ? buf[threadIdx.x - s] : 0;
            __syncthreads();
            buf[threadIdx.x] += t;
            __syncthreads();
        }
        int total = buf[1023];
        if (i < n) offs[i] = carry_s + buf[threadIdx.x] - v;
        __syncthreads();
        if (threadIdx.x == 0) carry_s += total;
        __syncthreads();
    }
    if (threadIdx.x == 0) offs[n] = carry_s;
}

// dis + graph-boundary starts, merged (both N-grids)
__global__ void dis_starts_kernel(const int* __restrict__ offs, float* __restrict__ dis,
                                  const int* __restrict__ batch, int* __restrict__ starts,
                                  int n, int G) {
    int i = blockIdx.x * blockDim.x + threadIdx.x;
    if (i >= n) return;
    dis[i] = rsqrtf((float)(offs[i + 1] - offs[i] + 1));  // +1 self-loop
    int b = batch[i];
    if (i == 0) {
        for (int g = 0; g <= b; g++) starts[g] = 0;
    } else {
        int bp = batch[i - 1];
        for (int g = bp + 1; g <= b; g++) starts[g] = i;
    }
    if (i == n - 1) {
        for (int g = b + 1; g <= G; g++) starts[g] = n;
    }
}

// countdown-cursor fill: reuses cnt (holds deg) as cursor via atomicSub
__global__ void fill_csr_kernel(const int* __restrict__ src, const int* __restrict__ dst,
                                const int* __restrict__ offs, int* __restrict__ cnt,
                                unsigned short* __restrict__ csr, int E) {
    int e = blockIdx.x * blockDim.x + threadIdx.x;
    if (e < E) {
        int d = dst[e];
        int p = atomicSub(&cnt[d], 1);  // returns old value in [1, deg]
        csr[offs[d] + p - 1] = (unsigned short)src[e];
    }
}

// all-layer W fp32 -> bf16 hi/lo planes (single launch, concatenated)
__global__ void wconv_kernel(const float* __restrict__ W1, const float* __restrict__ W2,
                             const float* __restrict__ W3, const float* __restrict__ W4,
                             short* __restrict__ Whi, short* __restrict__ Wlo) {
    int i = blockIdx.x * blockDim.x + threadIdx.x;
    const int n1 = HID * F_IN, nk = HID * HID;
    float v;
    if (i < n1) v = W1[i];
    else if (i < n1 + nk) v = W2[i - n1];
    else if (i < n1 + 2 * nk) v = W3[i - n1 - nk];
    else if (i < n1 + 3 * nk) v = W4[i - n1 - 2 * nk];
    else return;
    short h, l;
    split_bf16(v, h, l);
    Whi[i] = h;
    Wlo[i] = l;
}

// -------- XCD-affine chunked aggregation, half-wave edge-parallel --------
// out_i = dis_i * (dis_i*H_i + sum_j dis_j*H_j), written as bf16 hi/lo planes.
// One node per wave (no imbalance — R4/R5 lesson). Wave = 2 half-waves over the
// SAME 32 columns: half 0 takes even edges, half 1 odd edges; combined at the
// end via shfl_xor(32). Halves the serial batch chain, doubles loads in flight.
// chunk = blk % CHUNKS tracks round-robin XCD mapping (64-col slice per XCD for
// HID: 5.1 MB — the col-partition floor; 32-col slice for layer-1 x: 2.56 MB).
template <int F, int CHUNKS>
__global__ __launch_bounds__(64) void agg_chunk_kernel(
    const float* __restrict__ H, const float* __restrict__ dis,
    const int* __restrict__ offs, const unsigned short* __restrict__ csr,
    short* __restrict__ Ahi, short* __restrict__ Alo, int n) {
    int blk = blockIdx.x;
    int i = blk / CHUNKS;
    int chunk = blk % CHUNKS;
    int half = threadIdx.x >> 5;          // 0: even edges, 1: odd edges
    int t = threadIdx.x & 31;
    int col = chunk * 32 + t;
    const float* Hc = H + col;

    float di = dis[i];
    int e0 = offs[i], e1 = offs[i + 1];
    float a = (half == 0) ? di * Hc[(size_t)i * F] : 0.0f;   // self term once

    int k = e0 + half;
    // 8-deep pipeline per half => 16 edges in flight per wave
    for (; k + 14 < e1; k += 16) {
        int j0 = csr[k],      j1 = csr[k + 2],  j2 = csr[k + 4],  j3 = csr[k + 6];
        int j4 = csr[k + 8],  j5 = csr[k + 10], j6 = csr[k + 12], j7 = csr[k + 14];
        float d0 = dis[j0], d1 = dis[j1], d2 = dis[j2], d3 = dis[j3];
        float d4 = dis[j4], d5 = dis[j5], d6 = dis[j6], d7 = dis[j7];
        float r0 = Hc[(size_t)j0 * F], r1 = Hc[(size_t)j1 * F];
        float r2 = Hc[(size_t)j2 * F], r3 = Hc[(size_t)j3 * F];
        float r4 = Hc[(size_t)j4 * F], r5 = Hc[(size_t)j5 * F];
        float r6 = Hc[(size_t)j6 * F], r7 = Hc[(size_t)j7 * F];
        a += d0 * r0 + d1 * r1 + d2 * r2 + d3 * r3;
        a += d4 * r4 + d5 * r5 + d6 * r6 + d7 * r7;
    }
    for (; k < e1; k += 2) {
        int j = csr[k];
        a += dis[j] * Hc[(size_t)j * F];
    }

    a += __shfl_xor(a, 32);               // combine even/odd halves (width 64)
    if (half == 0) {
        a *= di;
        short h, l;
        split_bf16(a, h, l);
        Ahi[(size_t)i * F + col] = h;
        Alo[(size_t)i * F + col] = l;
    }
}

// -------- split-bf16 MFMA GEMM: C[M,N] = A[M,K] @ W[N,K]^T + bias --------
// A,W as bf16 hi/lo planes; 3 products hi*hi + hi*lo + lo*hi.
// 1D grid, XCD-affine swizzle: xcd = blk&7 owns a contiguous band of M-tiles.
__global__ __launch_bounds__(256) void gemm_mfma_kernel(
    const short* __restrict__ Ahi, const short* __restrict__ Alo,
    const short* __restrict__ Whi, const short* __restrict__ Wlo,
    const float* __restrict__ bias, float* __restrict__ C,
    int M, int K, int Nout, int MT, int MT8) {
    __shared__ __attribute__((aligned(16))) short lds[4][4096];

    // swizzled block decode: blk = xcd + 8*(n0t + 4*mt_local)
    int blk = blockIdx.x;
    int xcd = blk & 7;
    int r = blk >> 3;
    int n0t = r & 3;
    int mt = xcd * MT8 + (r >> 2);
    if (mt >= MT) return;                 // uniform across block; no barrier reached
    int m0 = mt * 128, n0 = n0t * 128;

    int tid = threadIdx.x;
    int w = tid >> 6, l = tid & 63;
    int lrow = l & 15, lq = l >> 4;

    const short* gp = (w == 0) ? Ahi : (w == 1) ? Alo : (w == 2) ? Whi : Wlo;
    int base_mn = (w < 2) ? m0 : n0;

    f32x4 acc[4][4];
    #pragma unroll
    for (int i = 0; i < 4; i++)
        #pragma unroll
        for (int j = 0; j < 4; j++) acc[i][j] = (f32x4){0.f, 0.f, 0.f, 0.f};

    int wm = w >> 1, wn = w & 1;

    for (int k0 = 0; k0 < K; k0 += 32) {
        const short* gbase = gp + (size_t)(base_mn + lrow) * K + (k0 + lq * 8);
        #pragma unroll
        for (int s = 0; s < 8; s++) {
            gload_lds16(gbase + (size_t)s * 16 * K, &lds[w][s * 64 * 8]);
        }
        __syncthreads();

        bf16x8 ah[4], al[4], wh[4], wl[4];
        #pragma unroll
        for (int i = 0; i < 4; i++) {
            int sA = wm * 4 + i;
            ah[i] = *(const bf16x8*)&lds[0][(sA * 64 + l) * 8];
            al[i] = *(const bf16x8*)&lds[1][(sA * 64 + l) * 8];
            int sW = wn * 4 + i;
            wh[i] = *(const bf16x8*)&lds[2][(sW * 64 + l) * 8];
            wl[i] = *(const bf16x8*)&lds[3][(sW * 64 + l) * 8];
        }
        #pragma unroll
        for (int i = 0; i < 4; i++)
            #pragma unroll
            for (int j = 0; j < 4; j++) {
                acc[i][j] = __builtin_amdgcn_mfma_f32_16x16x32_bf16(ah[i], wh[j], acc[i][j], 0, 0, 0);
                acc[i][j] = __builtin_amdgcn_mfma_f32_16x16x32_bf16(ah[i], wl[j], acc[i][j], 0, 0, 0);
                acc[i][j] = __builtin_amdgcn_mfma_f32_16x16x32_bf16(al[i], wh[j], acc[i][j], 0, 0, 0);
            }
        __syncthreads();
    }

    // epilogue: C/D layout col=lane&15, row=(lane>>4)*4+reg
    #pragma unroll
    for (int j = 0; j < 4; j++) {
        int col = n0 + (wn * 4 + j) * 16 + lrow;
        float bv = bias[col];
        #pragma unroll
        for (int i = 0; i < 4; i++) {
            int mrow = m0 + (wm * 4 + i) * 16 + lq * 4;
            #pragma unroll
            for (int rr = 0; rr < 4; rr++) {
                int mm = mrow + rr;
                if (mm < M) C[(size_t)mm * Nout + col] = acc[i][j][rr] + bv;
            }
        }
    }
}

// ---------------- pooling: per-layer segment max + fraction positive ----------------
// grid (G, 8), 64 threads: 2048 blocks for CU coverage.
__global__ __launch_bounds__(64) void pool_kernel(
    const float* __restrict__ H, const int* __restrict__ starts,
    float* __restrict__ out, int layer) {
    int g = blockIdx.x;
    int c = blockIdx.y * 64 + threadIdx.x;   // 0..511
    int s = starts[g], e = starts[g + 1];
    float mx = -INFINITY;
    int pos = 0;
    #pragma unroll 4
    for (int n = s; n < e; n++) {
        float v = H[(size_t)n * HID + c];
        mx = fmaxf(mx, v);
        pos += (v > 0.0f) ? 1 : 0;
    }
    float cntf = fmaxf((float)(e - s), 1.0f);
    out[(size_t)g * (8 * HID) + layer * HID + c] = mx;
    out[(size_t)g * (8 * HID) + 4 * HID + layer * HID + c] = (float)pos / cntf;
}

// ---------------- launcher ----------------
extern "C" void kernel_launch(void* const* d_in, const int* in_sizes, int n_in,
                              void* d_out, int out_size, void* d_ws, size_t ws_size,
                              hipStream_t stream) {
    const float* x     = (const float*)d_in[0];
    const int*   eidx  = (const int*)d_in[1];
    const int*   batch = (const int*)d_in[2];
    const float* W1 = (const float*)d_in[5];
    const float* b1 = (const float*)d_in[6];
    const float* W2 = (const float*)d_in[7];
    const float* b2 = (const float*)d_in[8];
    const float* W3 = (const float*)d_in[9];
    const float* b3 = (const float*)d_in[10];
    const float* W4 = (const float*)d_in[11];
    const float* b4 = (const float*)d_in[12];
    float* out = (float*)d_out;

    const int N = in_sizes[0] / F_IN;   // 20000
    const int E = in_sizes[1] / 2;      // 320000
    const int G = out_size / (8 * HID); // 256

    const int* src = eidx;
    const int* dst = eidx + E;

    // workspace layout (16B-aligned segments first)
    const size_t nW = (size_t)HID * F_IN + 3 * (size_t)HID * HID;
    char* w = (char*)d_ws;
    short* Ahi = (short*)w; w += (size_t)N * HID * sizeof(short);
    short* Alo = (short*)w; w += (size_t)N * HID * sizeof(short);
    float* H   = (float*)w; w += (size_t)N * HID * sizeof(float);
    short* Whi = (short*)w; w += nW * sizeof(short);
    short* Wlo = (short*)w; w += nW * sizeof(short);
    int* offs  = (int*)w;   w += (size_t)(N + 4) * sizeof(int);
    unsigned short* csr = (unsigned short*)w; w += (size_t)E * sizeof(unsigned short);
    int* cnt   = (int*)w;   w += (size_t)N * sizeof(int);
    float* dis = (float*)w; w += (size_t)N * sizeof(float);
    int* starts = (int*)w;  w += (size_t)(G + 1) * sizeof(int);

    const size_t wo1 = 0;
    const size_t wo2 = (size_t)HID * F_IN;
    const size_t wo3 = wo2 + (size_t)HID * HID;
    const size_t wo4 = wo3 + (size_t)HID * HID;

    const int TB = 256;
    // ---- preprocessing: CSR over dst, dis, graph boundaries, W planes ----
    zero_kernel<<<(N + TB - 1) / TB, TB, 0, stream>>>(cnt, N);
    count_in_kernel<<<(E + TB - 1) / TB, TB, 0, stream>>>(dst, cnt, E);
    scan_kernel<<<1, 1024, 0, stream>>>(cnt, offs, N);
    dis_starts_kernel<<<(N + TB - 1) / TB, TB, 0, stream>>>(offs, dis, batch, starts, N, G);
    fill_csr_kernel<<<(E + TB - 1) / TB, TB, 0, stream>>>(src, dst, offs, cnt, csr, E);
    wconv_kernel<<<((int)nW + TB - 1) / TB, TB, 0, stream>>>(W1, W2, W3, W4, Whi, Wlo);

    const int MT = (N + 127) / 128;        // 157 m-tiles
    const int MT8 = (MT + 7) / 8;          // per-XCD band
    const int gemm_blocks = 8 * MT8 * 4;   // 1D swizzled grid (some idle-guarded)
    dim3 pool_grid(G, HID / 64);

    // ---- layer 1: h1 = (A x) @ W1^T + b1 ----
    agg_chunk_kernel<F_IN, 4><<<N * 4, 64, 0, stream>>>(x, dis, offs, csr, Ahi, Alo, N);
    gemm_mfma_kernel<<<gemm_blocks, 256, 0, stream>>>(Ahi, Alo, Whi + wo1, Wlo + wo1, b1, H,
                                                      N, F_IN, HID, MT, MT8);
    pool_kernel<<<pool_grid, 64, 0, stream>>>(H, starts, out, 0);

    // ---- layers 2..4 ----
    const size_t wos[3] = {wo2, wo3, wo4};
    const float* bs_[3] = {b2, b3, b4};
    for (int ll = 0; ll < 3; ll++) {
        agg_chunk_kernel<HID, 16><<<N * 16, 64, 0, stream>>>(H, dis, offs, csr, Ahi, Alo, N);
        gemm_mfma_kernel<<<gemm_blocks, 256, 0, stream>>>(Ahi, Alo, Whi + wos[ll], Wlo + wos[ll], bs_[ll], H,
                                                          N, HID, HID, MT, MT8);
        pool_kernel<<<pool_grid, 64, 0, stream>>>(H, starts, out, ll + 1);
    }
}

// Round 8
// 785.059 us; speedup vs baseline: 1.0872x; 1.0872x over previous
//
#include <hip/hip_runtime.h>
#include <cfloat>
#include <cmath>

#define F_IN 128
#define HID 512

typedef short bf16x8 __attribute__((ext_vector_type(8)));
typedef float f32x4 __attribute__((ext_vector_type(4)));

// ---- bf16 split helpers (RNE) ----
__device__ static inline void split_bf16(float v, short& hi, short& lo) {
    unsigned u = __float_as_uint(v);
    unsigned r = u + 0x7FFF + ((u >> 16) & 1);
    hi = (short)(r >> 16);
    float hf = __uint_as_float(((unsigned)(unsigned short)hi) << 16);
    float res = v - hf;
    unsigned u2 = __float_as_uint(res);
    unsigned r2 = u2 + 0x7FFF + ((u2 >> 16) & 1);
    lo = (short)(r2 >> 16);
}

__device__ static inline void gload_lds16(const void* g, void* l) {
    __builtin_amdgcn_global_load_lds(
        (const __attribute__((address_space(1))) unsigned int*)g,
        (__attribute__((address_space(3))) unsigned int*)l,
        16, 0, 0);
}

// ---------------- small utility kernels ----------------

__global__ void zero_kernel(int* __restrict__ a, int n) {
    int i = blockIdx.x * blockDim.x + threadIdx.x;
    if (i < n) a[i] = 0;
}

__global__ void count_in_kernel(const int* __restrict__ dst, int* __restrict__ cnt, int E) {
    int e = blockIdx.x * blockDim.x + threadIdx.x;
    if (e < E) atomicAdd(&cnt[dst[e]], 1);
}

// single-block scan (exclusive prefix sum); also writes offs[n] = total
__global__ void scan_kernel(const int* __restrict__ cnt, int* __restrict__ offs, int n) {
    __shared__ int buf[1024];
    __shared__ int carry_s;
    if (threadIdx.x == 0) carry_s = 0;
    __syncthreads();
    for (int base = 0; base < n; base += 1024) {
        int i = base + threadIdx.x;
        int v = (i < n) ? cnt[i] : 0;
        buf[threadIdx.x] = v;
        __syncthreads();
        for (int s = 1; s < 1024; s <<= 1) {
            int t = (threadIdx.x >= s) ? buf[threadIdx.x - s] : 0;
            __syncthreads();
            buf[threadIdx.x] += t;
            __syncthreads();
        }
        int total = buf[1023];
        if (i < n) offs[i] = carry_s + buf[threadIdx.x] - v;
        __syncthreads();
        if (threadIdx.x == 0) carry_s += total;
        __syncthreads();
    }
    if (threadIdx.x == 0) offs[n] = carry_s;
}

// dis + graph-boundary starts, merged (both N-grids)
__global__ void dis_starts_kernel(const int* __restrict__ offs, float* __restrict__ dis,
                                  const int* __restrict__ batch, int* __restrict__ starts,
                                  int n, int G) {
    int i = blockIdx.x * blockDim.x + threadIdx.x;
    if (i >= n) return;
    dis[i] = rsqrtf((float)(offs[i + 1] - offs[i] + 1));  // +1 self-loop
    int b = batch[i];
    if (i == 0) {
        for (int g = 0; g <= b; g++) starts[g] = 0;
    } else {
        int bp = batch[i - 1];
        for (int g = bp + 1; g <= b; g++) starts[g] = i;
    }
    if (i == n - 1) {
        for (int g = b + 1; g <= G; g++) starts[g] = n;
    }
}

// countdown-cursor fill: reuses cnt (holds deg) as cursor via atomicSub
__global__ void fill_csr_kernel(const int* __restrict__ src, const int* __restrict__ dst,
                                const int* __restrict__ offs, int* __restrict__ cnt,
                                unsigned short* __restrict__ csr, int E) {
    int e = blockIdx.x * blockDim.x + threadIdx.x;
    if (e < E) {
        int d = dst[e];
        int p = atomicSub(&cnt[d], 1);  // returns old value in [1, deg]
        csr[offs[d] + p - 1] = (unsigned short)src[e];
    }
}

// all-layer W fp32 -> bf16 hi/lo planes (single launch, concatenated)
__global__ void wconv_kernel(const float* __restrict__ W1, const float* __restrict__ W2,
                             const float* __restrict__ W3, const float* __restrict__ W4,
                             short* __restrict__ Whi, short* __restrict__ Wlo) {
    int i = blockIdx.x * blockDim.x + threadIdx.x;
    const int n1 = HID * F_IN, nk = HID * HID;
    float v;
    if (i < n1) v = W1[i];
    else if (i < n1 + nk) v = W2[i - n1];
    else if (i < n1 + 2 * nk) v = W3[i - n1 - nk];
    else if (i < n1 + 3 * nk) v = W4[i - n1 - 2 * nk];
    else return;
    short h, l;
    split_bf16(v, h, l);
    Whi[i] = h;
    Wlo[i] = l;
}

// -------- XCD-affine chunked aggregation + fused bf16-pair conversion --------
// out_i = dis_i * (dis_i*H_i + sum_j dis_j*H_j), written as bf16 hi/lo planes.
// R6-proven config: 1 wave = 1 node x 64 cols, 8-deep pipeline, 85 us.
// (R4: 16-deep +2node = 91; R5: 4-node = ~110; R7: half-wave 16-chunk = 143.)
template <int F, int CHUNKS>
__global__ __launch_bounds__(64) void agg_chunk_kernel(
    const float* __restrict__ H, const float* __restrict__ dis,
    const int* __restrict__ offs, const unsigned short* __restrict__ csr,
    short* __restrict__ Ahi, short* __restrict__ Alo, int n) {
    int blk = blockIdx.x;
    int i = blk / CHUNKS;
    int chunk = blk % CHUNKS;
    int col = chunk * 64 + threadIdx.x;
    const float* Hc = H + col;

    float di = dis[i];
    float a = di * Hc[(size_t)i * F];
    int e = offs[i], e1 = offs[i + 1];
    // 8-way software-pipelined gather
    for (; e + 8 <= e1; e += 8) {
        int j0 = csr[e],     j1 = csr[e + 1], j2 = csr[e + 2], j3 = csr[e + 3];
        int j4 = csr[e + 4], j5 = csr[e + 5], j6 = csr[e + 6], j7 = csr[e + 7];
        float d0 = dis[j0], d1 = dis[j1], d2 = dis[j2], d3 = dis[j3];
        float d4 = dis[j4], d5 = dis[j5], d6 = dis[j6], d7 = dis[j7];
        float r0 = Hc[(size_t)j0 * F], r1 = Hc[(size_t)j1 * F];
        float r2 = Hc[(size_t)j2 * F], r3 = Hc[(size_t)j3 * F];
        float r4 = Hc[(size_t)j4 * F], r5 = Hc[(size_t)j5 * F];
        float r6 = Hc[(size_t)j6 * F], r7 = Hc[(size_t)j7 * F];
        a += d0 * r0 + d1 * r1 + d2 * r2 + d3 * r3;
        a += d4 * r4 + d5 * r5 + d6 * r6 + d7 * r7;
    }
    for (; e < e1; e++) {
        int j = csr[e];
        a += dis[j] * Hc[(size_t)j * F];
    }
    a *= di;
    short h, l;
    split_bf16(a, h, l);
    Ahi[(size_t)i * F + col] = h;
    Alo[(size_t)i * F + col] = l;
}

// -------- split-bf16 MFMA GEMM: C[M,N] = A[M,K] @ W[N,K]^T + bias --------
// A,W as bf16 hi/lo planes; 3 products hi*hi + hi*lo + lo*hi.
// BM=64, BN=128, 128 threads (2 waves, each 64x64 = proven per-wave shape).
// 1252 blocks (vs 628) to fix R5's measured 13% occupancy wave starvation.
// m-major block order: the 4 n-tiles sharing an A-band co-schedule (A L2-hot).
__global__ __launch_bounds__(128) void gemm_mfma_kernel(
    const short* __restrict__ Ahi, const short* __restrict__ Alo,
    const short* __restrict__ Whi, const short* __restrict__ Wlo,
    const float* __restrict__ bias, float* __restrict__ C,
    int M, int K, int Nout) {
    __shared__ __attribute__((aligned(16))) short ldsA[2][4][512];   // 8 KB
    __shared__ __attribute__((aligned(16))) short ldsW[2][8][512];   // 16 KB

    int blk = blockIdx.x;
    int mt = blk >> 2, nt = blk & 3;
    int m0 = mt * 64, n0 = nt * 128;

    int tid = threadIdx.x;
    int w = tid >> 6, l = tid & 63;
    int lrow = l & 15, lq = l >> 4;

    f32x4 acc[4][4];
    #pragma unroll
    for (int i = 0; i < 4; i++)
        #pragma unroll
        for (int j = 0; j < 4; j++) acc[i][j] = (f32x4){0.f, 0.f, 0.f, 0.f};

    for (int k0 = 0; k0 < K; k0 += 32) {
        // 24 stage units (A: 4 msub x 2 planes; W: 8 nsub x 2 planes); 12 per wave
        #pragma unroll
        for (int uu = 0; uu < 12; uu++) {
            int u = w * 12 + uu;
            if (u < 8) {
                int p = u >> 2, s = u & 3;
                const short* srcp = p ? Alo : Ahi;
                gload_lds16(srcp + (size_t)(m0 + s * 16 + lrow) * K + k0 + lq * 8,
                            &ldsA[p][s][l * 8]);
            } else {
                int v = u - 8;
                int p = v >> 3, s = v & 7;
                const short* srcp = p ? Wlo : Whi;
                gload_lds16(srcp + (size_t)(n0 + s * 16 + lrow) * K + k0 + lq * 8,
                            &ldsW[p][s][l * 8]);
            }
        }
        __syncthreads();

        bf16x8 ah[4], al[4], wh[4], wl[4];
        #pragma unroll
        for (int i = 0; i < 4; i++) {
            ah[i] = *(const bf16x8*)&ldsA[0][i][l * 8];
            al[i] = *(const bf16x8*)&ldsA[1][i][l * 8];
            wh[i] = *(const bf16x8*)&ldsW[0][w * 4 + i][l * 8];
            wl[i] = *(const bf16x8*)&ldsW[1][w * 4 + i][l * 8];
        }
        #pragma unroll
        for (int i = 0; i < 4; i++)
            #pragma unroll
            for (int j = 0; j < 4; j++) {
                acc[i][j] = __builtin_amdgcn_mfma_f32_16x16x32_bf16(ah[i], wh[j], acc[i][j], 0, 0, 0);
                acc[i][j] = __builtin_amdgcn_mfma_f32_16x16x32_bf16(ah[i], wl[j], acc[i][j], 0, 0, 0);
                acc[i][j] = __builtin_amdgcn_mfma_f32_16x16x32_bf16(al[i], wh[j], acc[i][j], 0, 0, 0);
            }
        __syncthreads();
    }

    // epilogue: C/D layout col=lane&15, row=(lane>>4)*4+reg
    #pragma unroll
    for (int j = 0; j < 4; j++) {
        int col = n0 + (w * 4 + j) * 16 + lrow;
        float bv = bias[col];
        #pragma unroll
        for (int i = 0; i < 4; i++) {
            int mrow = m0 + i * 16 + lq * 4;
            #pragma unroll
            for (int rr = 0; rr < 4; rr++) {
                int mm = mrow + rr;
                if (mm < M) C[(size_t)mm * Nout + col] = acc[i][j][rr] + bv;
            }
        }
    }
}

// ---------------- pooling: per-layer segment max + fraction positive ----------------
// grid (G, 8), 64 threads: 2048 blocks for CU coverage.
__global__ __launch_bounds__(64) void pool_kernel(
    const float* __restrict__ H, const int* __restrict__ starts,
    float* __restrict__ out, int layer) {
    int g = blockIdx.x;
    int c = blockIdx.y * 64 + threadIdx.x;   // 0..511
    int s = starts[g], e = starts[g + 1];
    float mx = -INFINITY;
    int pos = 0;
    #pragma unroll 4
    for (int n = s; n < e; n++) {
        float v = H[(size_t)n * HID + c];
        mx = fmaxf(mx, v);
        pos += (v > 0.0f) ? 1 : 0;
    }
    float cntf = fmaxf((float)(e - s), 1.0f);
    out[(size_t)g * (8 * HID) + layer * HID + c] = mx;
    out[(size_t)g * (8 * HID) + 4 * HID + layer * HID + c] = (float)pos / cntf;
}

// ---------------- launcher ----------------
extern "C" void kernel_launch(void* const* d_in, const int* in_sizes, int n_in,
                              void* d_out, int out_size, void* d_ws, size_t ws_size,
                              hipStream_t stream) {
    const float* x     = (const float*)d_in[0];
    const int*   eidx  = (const int*)d_in[1];
    const int*   batch = (const int*)d_in[2];
    const float* W1 = (const float*)d_in[5];
    const float* b1 = (const float*)d_in[6];
    const float* W2 = (const float*)d_in[7];
    const float* b2 = (const float*)d_in[8];
    const float* W3 = (const float*)d_in[9];
    const float* b3 = (const float*)d_in[10];
    const float* W4 = (const float*)d_in[11];
    const float* b4 = (const float*)d_in[12];
    float* out = (float*)d_out;

    const int N = in_sizes[0] / F_IN;   // 20000
    const int E = in_sizes[1] / 2;      // 320000
    const int G = out_size / (8 * HID); // 256

    const int* src = eidx;
    const int* dst = eidx + E;

    // workspace layout (16B-aligned segments first)
    const size_t nW = (size_t)HID * F_IN + 3 * (size_t)HID * HID;
    char* w = (char*)d_ws;
    short* Ahi = (short*)w; w += (size_t)N * HID * sizeof(short);
    short* Alo = (short*)w; w += (size_t)N * HID * sizeof(short);
    float* H   = (float*)w; w += (size_t)N * HID * sizeof(float);
    short* Whi = (short*)w; w += nW * sizeof(short);
    short* Wlo = (short*)w; w += nW * sizeof(short);
    int* offs  = (int*)w;   w += (size_t)(N + 4) * sizeof(int);
    unsigned short* csr = (unsigned short*)w; w += (size_t)E * sizeof(unsigned short);
    int* cnt   = (int*)w;   w += (size_t)N * sizeof(int);
    float* dis = (float*)w; w += (size_t)N * sizeof(float);
    int* starts = (int*)w;  w += (size_t)(G + 1) * sizeof(int);

    const size_t wo1 = 0;
    const size_t wo2 = (size_t)HID * F_IN;
    const size_t wo3 = wo2 + (size_t)HID * HID;
    const size_t wo4 = wo3 + (size_t)HID * HID;

    const int TB = 256;
    // ---- preprocessing: CSR over dst, dis, graph boundaries, W planes ----
    zero_kernel<<<(N + TB - 1) / TB, TB, 0, stream>>>(cnt, N);
    count_in_kernel<<<(E + TB - 1) / TB, TB, 0, stream>>>(dst, cnt, E);
    scan_kernel<<<1, 1024, 0, stream>>>(cnt, offs, N);
    dis_starts_kernel<<<(N + TB - 1) / TB, TB, 0, stream>>>(offs, dis, batch, starts, N, G);
    fill_csr_kernel<<<(E + TB - 1) / TB, TB, 0, stream>>>(src, dst, offs, cnt, csr, E);
    wconv_kernel<<<((int)nW + TB - 1) / TB, TB, 0, stream>>>(W1, W2, W3, W4, Whi, Wlo);

    const int MT = (N + 63) / 64;          // 313 m-tiles
    const int gemm_blocks = MT * 4;        // 1252 blocks, m-major
    dim3 pool_grid(G, HID / 64);

    // ---- layer 1: h1 = (A x) @ W1^T + b1 ----
    agg_chunk_kernel<F_IN, 2><<<N * 2, 64, 0, stream>>>(x, dis, offs, csr, Ahi, Alo, N);
    gemm_mfma_kernel<<<gemm_blocks, 128, 0, stream>>>(Ahi, Alo, Whi + wo1, Wlo + wo1, b1, H,
                                                      N, F_IN, HID);
    pool_kernel<<<pool_grid, 64, 0, stream>>>(H, starts, out, 0);

    // ---- layers 2..4 ----
    const size_t wos[3] = {wo2, wo3, wo4};
    const float* bs_[3] = {b2, b3, b4};
    for (int ll = 0; ll < 3; ll++) {
        agg_chunk_kernel<HID, 8><<<N * 8, 64, 0, stream>>>(H, dis, offs, csr, Ahi, Alo, N);
        gemm_mfma_kernel<<<gemm_blocks, 128, 0, stream>>>(Ahi, Alo, Whi + wos[ll], Wlo + wos[ll], bs_[ll], H,
                                                          N, HID, HID);
        pool_kernel<<<pool_grid, 64, 0, stream>>>(H, starts, out, ll + 1);
    }
}

// Round 9
// 728.641 us; speedup vs baseline: 1.1713x; 1.0774x over previous
//
#include <hip/hip_runtime.h>
#include <cfloat>
#include <cmath>

#define F_IN 128
#define HID 512

typedef short bf16x8 __attribute__((ext_vector_type(8)));
typedef float f32x4 __attribute__((ext_vector_type(4)));

// ---- bf16 split helpers (RNE) ----
__device__ static inline void split_bf16(float v, short& hi, short& lo) {
    unsigned u = __float_as_uint(v);
    unsigned r = u + 0x7FFF + ((u >> 16) & 1);
    hi = (short)(r >> 16);
    float hf = __uint_as_float(((unsigned)(unsigned short)hi) << 16);
    float res = v - hf;
    unsigned u2 = __float_as_uint(res);
    unsigned r2 = u2 + 0x7FFF + ((u2 >> 16) & 1);
    lo = (short)(r2 >> 16);
}

// ---------------- small utility kernels ----------------

__global__ void zero_kernel(int* __restrict__ a, int n) {
    int i = blockIdx.x * blockDim.x + threadIdx.x;
    if (i < n) a[i] = 0;
}

__global__ void count_in_kernel(const int* __restrict__ dst, int* __restrict__ cnt, int E) {
    int e = blockIdx.x * blockDim.x + threadIdx.x;
    if (e < E) atomicAdd(&cnt[dst[e]], 1);
}

// single-block scan (exclusive prefix sum); also writes offs[n] = total
__global__ void scan_kernel(const int* __restrict__ cnt, int* __restrict__ offs, int n) {
    __shared__ int buf[1024];
    __shared__ int carry_s;
    if (threadIdx.x == 0) carry_s = 0;
    __syncthreads();
    for (int base = 0; base < n; base += 1024) {
        int i = base + threadIdx.x;
        int v = (i < n) ? cnt[i] : 0;
        buf[threadIdx.x] = v;
        __syncthreads();
        for (int s = 1; s < 1024; s <<= 1) {
            int t = (threadIdx.x >= s) ? buf[threadIdx.x - s] : 0;
            __syncthreads();
            buf[threadIdx.x] += t;
            __syncthreads();
        }
        int total = buf[1023];
        if (i < n) offs[i] = carry_s + buf[threadIdx.x] - v;
        __syncthreads();
        if (threadIdx.x == 0) carry_s += total;
        __syncthreads();
    }
    if (threadIdx.x == 0) offs[n] = carry_s;
}

// dis + graph-boundary starts, merged (both N-grids)
__global__ void dis_starts_kernel(const int* __restrict__ offs, float* __restrict__ dis,
                                  const int* __restrict__ batch, int* __restrict__ starts,
                                  int n, int G) {
    int i = blockIdx.x * blockDim.x + threadIdx.x;
    if (i >= n) return;
    dis[i] = rsqrtf((float)(offs[i + 1] - offs[i] + 1));  // +1 self-loop
    int b = batch[i];
    if (i == 0) {
        for (int g = 0; g <= b; g++) starts[g] = 0;
    } else {
        int bp = batch[i - 1];
        for (int g = bp + 1; g <= b; g++) starts[g] = i;
    }
    if (i == n - 1) {
        for (int g = b + 1; g <= G; g++) starts[g] = n;
    }
}

// countdown-cursor fill: reuses cnt (holds deg) as cursor via atomicSub
__global__ void fill_csr_kernel(const int* __restrict__ src, const int* __restrict__ dst,
                                const int* __restrict__ offs, int* __restrict__ cnt,
                                unsigned short* __restrict__ csr, int E) {
    int e = blockIdx.x * blockDim.x + threadIdx.x;
    if (e < E) {
        int d = dst[e];
        int p = atomicSub(&cnt[d], 1);  // returns old value in [1, deg]
        csr[offs[d] + p - 1] = (unsigned short)src[e];
    }
}

// all-layer W fp32 -> bf16 hi/lo planes in MFMA-FRAGMENT order.
// frag addr = base + ((nt16*KT + kt)*64 + lane)*8 + (k&7),
// lane = (n&15) + 16*((k>>3)&3), kt = k>>5. KT=4 for W1, 16 for W2-4.
__global__ void wconv_kernel(const float* __restrict__ W1, const float* __restrict__ W2,
                             const float* __restrict__ W3, const float* __restrict__ W4,
                             short* __restrict__ Whi, short* __restrict__ Wlo) {
    int i = blockIdx.x * blockDim.x + threadIdx.x;
    const int n1 = HID * F_IN, nk = HID * HID;
    const float* Wp; int idx, KT; size_t base;
    if (i < n1)               { Wp = W1; idx = i;               KT = 4;  base = 0; }
    else if (i < n1 + nk)     { Wp = W2; idx = i - n1;          KT = 16; base = 65536; }
    else if (i < n1 + 2 * nk) { Wp = W3; idx = i - n1 - nk;     KT = 16; base = 65536 + 262144; }
    else if (i < n1 + 3 * nk) { Wp = W4; idx = i - n1 - 2 * nk; KT = 16; base = 65536 + 524288; }
    else return;
    int K = KT * 32;
    int n = idx / K, k = idx % K;
    short h, l;
    split_bf16(Wp[idx], h, l);
    int lane = (n & 15) + 16 * ((k >> 3) & 3);
    size_t a = base + (((size_t)((n >> 4) * KT + (k >> 5))) * 64 + lane) * 8 + (k & 7);
    Whi[a] = h;
    Wlo[a] = l;
}

// -------- XCD-affine chunked aggregation, emits MFMA-fragment-ordered planes --------
// out_i = dis_i * (dis_i*H_i + sum_j dis_j*H_j). Gather side is the R6-proven
// config: 1 wave = 1 node x 64 cols, 8-deep pipeline (85 us). Store side writes
// fragment layout so the GEMM can load operands global->VGPR with no LDS.
template <int F, int CHUNKS>
__global__ __launch_bounds__(64) void agg_chunk_kernel(
    const float* __restrict__ H, const float* __restrict__ dis,
    const int* __restrict__ offs, const unsigned short* __restrict__ csr,
    short* __restrict__ Ahi, short* __restrict__ Alo, int n) {
    int blk = blockIdx.x;
    int i = blk / CHUNKS;
    int chunk = blk % CHUNKS;
    int col = chunk * 64 + threadIdx.x;
    const float* Hc = H + col;

    float di = dis[i];
    float a = di * Hc[(size_t)i * F];
    int e = offs[i], e1 = offs[i + 1];
    for (; e + 8 <= e1; e += 8) {
        int j0 = csr[e],     j1 = csr[e + 1], j2 = csr[e + 2], j3 = csr[e + 3];
        int j4 = csr[e + 4], j5 = csr[e + 5], j6 = csr[e + 6], j7 = csr[e + 7];
        float d0 = dis[j0], d1 = dis[j1], d2 = dis[j2], d3 = dis[j3];
        float d4 = dis[j4], d5 = dis[j5], d6 = dis[j6], d7 = dis[j7];
        float r0 = Hc[(size_t)j0 * F], r1 = Hc[(size_t)j1 * F];
        float r2 = Hc[(size_t)j2 * F], r3 = Hc[(size_t)j3 * F];
        float r4 = Hc[(size_t)j4 * F], r5 = Hc[(size_t)j5 * F];
        float r6 = Hc[(size_t)j6 * F], r7 = Hc[(size_t)j7 * F];
        a += d0 * r0 + d1 * r1 + d2 * r2 + d3 * r3;
        a += d4 * r4 + d5 * r5 + d6 * r6 + d7 * r7;
    }
    for (; e < e1; e++) {
        int j = csr[e];
        a += dis[j] * Hc[(size_t)j * F];
    }
    a *= di;
    short h, l;
    split_bf16(a, h, l);
    // fragment-order store: subtile = i>>4, kt = col>>5, lane = (i&15)+16*((col>>3)&3)
    size_t ad = (((size_t)((i >> 4) * (F / 32) + (col >> 5))) * 64
                 + ((i & 15) + 16 * ((col >> 3) & 3))) * 8 + (col & 7);
    Ahi[ad] = h;
    Alo[ad] = l;
}

// -------- barrier-free split-bf16 MFMA GEMM on fragment-ordered operands --------
// C[M,512] = A[M,K] @ W[512,K]^T + bias; 3 products hi*hi + hi*lo + lo*hi.
// No LDS, no __syncthreads: per-lane 16B fragment loads global->VGPR, register
// double-buffered across kt. Wave = independent 64x64 tile; block = 4 waves.
template <int KT>
__global__ __launch_bounds__(256) void gemm_frag_kernel(
    const short* __restrict__ Ah_, const short* __restrict__ Al_,
    const short* __restrict__ Wh_, const short* __restrict__ Wl_,
    const float* __restrict__ bias, float* __restrict__ C,
    int M, int Nout) {
    int blk = blockIdx.x;
    int mb = blk >> 2, nb = blk & 3;
    int w = threadIdx.x >> 6, l = threadIdx.x & 63;
    int mt = mb * 2 + (w >> 1);       // wave m-tile (64 rows)
    int nt = nb * 2 + (w & 1);        // wave n-tile (64 cols)
    int ms0 = mt * 4, ns0 = nt * 4;   // 16-row/col subtile indices

    const bf16x8* Ah = (const bf16x8*)Ah_;
    const bf16x8* Al = (const bf16x8*)Al_;
    const bf16x8* Wh = (const bf16x8*)Wh_;
    const bf16x8* Wl = (const bf16x8*)Wl_;

    size_t aoff[4], woff[4];
    #pragma unroll
    for (int i = 0; i < 4; i++) {
        aoff[i] = (size_t)(ms0 + i) * KT * 64 + l;
        woff[i] = (size_t)(ns0 + i) * KT * 64 + l;
    }

    f32x4 acc[4][4];
    #pragma unroll
    for (int i = 0; i < 4; i++)
        #pragma unroll
        for (int j = 0; j < 4; j++) acc[i][j] = (f32x4){0.f, 0.f, 0.f, 0.f};

    bf16x8 ah[2][4], al[2][4], wh[2][4], wl[2][4];
    #pragma unroll
    for (int i = 0; i < 4; i++) {
        ah[0][i] = Ah[aoff[i]];
        al[0][i] = Al[aoff[i]];
        wh[0][i] = Wh[woff[i]];
        wl[0][i] = Wl[woff[i]];
    }

    #pragma unroll
    for (int kt = 0; kt < KT; kt++) {
        int cur = kt & 1, nxt = cur ^ 1;
        if (kt + 1 < KT) {
            #pragma unroll
            for (int i = 0; i < 4; i++) {
                size_t ka = aoff[i] + (size_t)(kt + 1) * 64;
                size_t kw = woff[i] + (size_t)(kt + 1) * 64;
                ah[nxt][i] = Ah[ka];
                al[nxt][i] = Al[ka];
                wh[nxt][i] = Wh[kw];
                wl[nxt][i] = Wl[kw];
            }
        }
        #pragma unroll
        for (int i = 0; i < 4; i++)
            #pragma unroll
            for (int j = 0; j < 4; j++) {
                acc[i][j] = __builtin_amdgcn_mfma_f32_16x16x32_bf16(ah[cur][i], wh[cur][j], acc[i][j], 0, 0, 0);
                acc[i][j] = __builtin_amdgcn_mfma_f32_16x16x32_bf16(ah[cur][i], wl[cur][j], acc[i][j], 0, 0, 0);
                acc[i][j] = __builtin_amdgcn_mfma_f32_16x16x32_bf16(al[cur][i], wh[cur][j], acc[i][j], 0, 0, 0);
            }
    }

    // epilogue: C/D layout col=lane&15, row=(lane>>4)*4+reg
    int lrow = l & 15, lq = l >> 4;
    #pragma unroll
    for (int j = 0; j < 4; j++) {
        int col = (ns0 + j) * 16 + lrow;
        float bv = bias[col];
        #pragma unroll
        for (int i = 0; i < 4; i++) {
            int mrow = (ms0 + i) * 16 + lq * 4;
            #pragma unroll
            for (int rr = 0; rr < 4; rr++) {
                int mm = mrow + rr;
                if (mm < M) C[(size_t)mm * Nout + col] = acc[i][j][rr] + bv;
            }
        }
    }
}

// ---------------- pooling: per-layer segment max + fraction positive ----------------
__global__ __launch_bounds__(64) void pool_kernel(
    const float* __restrict__ H, const int* __restrict__ starts,
    float* __restrict__ out, int layer) {
    int g = blockIdx.x;
    int c = blockIdx.y * 64 + threadIdx.x;   // 0..511
    int s = starts[g], e = starts[g + 1];
    float mx = -INFINITY;
    int pos = 0;
    #pragma unroll 4
    for (int n = s; n < e; n++) {
        float v = H[(size_t)n * HID + c];
        mx = fmaxf(mx, v);
        pos += (v > 0.0f) ? 1 : 0;
    }
    float cntf = fmaxf((float)(e - s), 1.0f);
    out[(size_t)g * (8 * HID) + layer * HID + c] = mx;
    out[(size_t)g * (8 * HID) + 4 * HID + layer * HID + c] = (float)pos / cntf;
}

// ---------------- launcher ----------------
extern "C" void kernel_launch(void* const* d_in, const int* in_sizes, int n_in,
                              void* d_out, int out_size, void* d_ws, size_t ws_size,
                              hipStream_t stream) {
    const float* x     = (const float*)d_in[0];
    const int*   eidx  = (const int*)d_in[1];
    const int*   batch = (const int*)d_in[2];
    const float* W1 = (const float*)d_in[5];
    const float* b1 = (const float*)d_in[6];
    const float* W2 = (const float*)d_in[7];
    const float* b2 = (const float*)d_in[8];
    const float* W3 = (const float*)d_in[9];
    const float* b3 = (const float*)d_in[10];
    const float* W4 = (const float*)d_in[11];
    const float* b4 = (const float*)d_in[12];
    float* out = (float*)d_out;

    const int N = in_sizes[0] / F_IN;   // 20000
    const int E = in_sizes[1] / 2;      // 320000
    const int G = out_size / (8 * HID); // 256

    const int* src = eidx;
    const int* dst = eidx + E;

    // workspace layout (16B-aligned segments first)
    const int MT16P = 1260;                           // padded 16-row subtiles (>= 1256 touched)
    const size_t nAfrag = (size_t)MT16P * 16 * 512;   // KT=16 frag elems (layer-1 KT=4 fits inside)
    const size_t nWfrag = 65536 + 3 * 262144;         // W1(KT=4) + W2..W4(KT=16)
    char* w = (char*)d_ws;
    short* Ahi = (short*)w; w += nAfrag * sizeof(short);
    short* Alo = (short*)w; w += nAfrag * sizeof(short);
    float* H   = (float*)w; w += (size_t)N * HID * sizeof(float);
    short* Whi = (short*)w; w += nWfrag * sizeof(short);
    short* Wlo = (short*)w; w += nWfrag * sizeof(short);
    int* offs  = (int*)w;   w += (size_t)(N + 4) * sizeof(int);
    unsigned short* csr = (unsigned short*)w; w += (size_t)E * sizeof(unsigned short);
    int* cnt   = (int*)w;   w += (size_t)N * sizeof(int);
    float* dis = (float*)w; w += (size_t)N * sizeof(float);
    int* starts = (int*)w;  w += (size_t)(G + 1) * sizeof(int);

    const size_t wo1 = 0, wo2 = 65536, wo3 = 65536 + 262144, wo4 = 65536 + 524288;
    const size_t nWtot = (size_t)HID * F_IN + 3 * (size_t)HID * HID;

    const int TB = 256;
    // ---- preprocessing: CSR over dst, dis, graph boundaries, W frag planes ----
    zero_kernel<<<(N + TB - 1) / TB, TB, 0, stream>>>(cnt, N);
    count_in_kernel<<<(E + TB - 1) / TB, TB, 0, stream>>>(dst, cnt, E);
    scan_kernel<<<1, 1024, 0, stream>>>(cnt, offs, N);
    dis_starts_kernel<<<(N + TB - 1) / TB, TB, 0, stream>>>(offs, dis, batch, starts, N, G);
    fill_csr_kernel<<<(E + TB - 1) / TB, TB, 0, stream>>>(src, dst, offs, cnt, csr, E);
    wconv_kernel<<<((int)nWtot + TB - 1) / TB, TB, 0, stream>>>(W1, W2, W3, W4, Whi, Wlo);

    const int MB = 157;                    // ceil(313 wave-m-tiles / 2)
    const int gemm_blocks = MB * 4;        // 628 blocks x 4 waves
    dim3 pool_grid(G, HID / 64);

    // ---- layer 1: h1 = (A x) @ W1^T + b1 ----
    agg_chunk_kernel<F_IN, 2><<<N * 2, 64, 0, stream>>>(x, dis, offs, csr, Ahi, Alo, N);
    gemm_frag_kernel<4><<<gemm_blocks, 256, 0, stream>>>(Ahi, Alo, Whi + wo1, Wlo + wo1, b1, H, N, HID);
    pool_kernel<<<pool_grid, 64, 0, stream>>>(H, starts, out, 0);

    // ---- layers 2..4 ----
    const size_t wos[3] = {wo2, wo3, wo4};
    const float* bs_[3] = {b2, b3, b4};
    for (int ll = 0; ll < 3; ll++) {
        agg_chunk_kernel<HID, 8><<<N * 8, 64, 0, stream>>>(H, dis, offs, csr, Ahi, Alo, N);
        gemm_frag_kernel<16><<<gemm_blocks, 256, 0, stream>>>(Ahi, Alo, Whi + wos[ll], Wlo + wos[ll], bs_[ll], H, N, HID);
        pool_kernel<<<pool_grid, 64, 0, stream>>>(H, starts, out, ll + 1);
    }
}